// Round 1
// baseline (1002.323 us; speedup 1.0000x reference)
//
#include <hip/hip_runtime.h>
#include <math.h>

// Problem constants (match reference)
#define NPIX 102400          // B*H*W = 8*80*160
#define NSEED 4
#define RTOT (NPIX * NSEED)  // 409600 rows
#define GG 8                 // cost groups
#define DD 64                // disparity candidates
#define EE 128               // embed dim
#define K1 72                // G*9
#define K2 128               // E
#define K3 159               // E + 31
#define NFREQ 15
#define BM 64                // rows per block (16 pixels x 4 seeds)
#define PAD 68               // padded row length (floats) for transposed act buffers; 68*4 bytes keeps rows 16B-aligned

__device__ __forceinline__ float gelu_exact(float x) {
    return 0.5f * x * (1.0f + erff(x * 0.7071067811865475f));
}

// acc[r][c] += sXT[k][ty*4+r] * W[k][tx*8+c], k in [0,K)
template <int K>
__device__ __forceinline__ void mm_tile(const float* sXT, const float* __restrict__ W,
                                        int tx, int ty, float acc[4][8]) {
#pragma unroll 4
    for (int k = 0; k < K; ++k) {
        const float4 a  = *(const float4*)(sXT + k * PAD + ty * 4);
        const float4 w0 = *(const float4*)(W + k * EE + tx * 8);
        const float4 w1 = *(const float4*)(W + k * EE + tx * 8 + 4);
        const float av[4] = {a.x, a.y, a.z, a.w};
        const float wv[8] = {w0.x, w0.y, w0.z, w0.w, w1.x, w1.y, w1.z, w1.w};
#pragma unroll
        for (int r = 0; r < 4; ++r)
#pragma unroll
            for (int c = 0; c < 8; ++c)
                acc[r][c] += av[r] * wv[c];
    }
}

__global__ __launch_bounds__(256, 2)
void Propagation_85315230368231_kernel(const float* __restrict__ cost_volume,
                                       const int* __restrict__ label_seed,
                                       const float* __restrict__ W1,
                                       const float* __restrict__ b1,
                                       const float* __restrict__ W2,
                                       const float* __restrict__ b2,
                                       const float* __restrict__ Wp,
                                       float* __restrict__ out) {
    // Transposed activation buffers: [k][row], row-major with PAD stride.
    // sX3T rows [0,72)   : gathered cost (stage-1 input) -- dead after stage 1
    // sX3T rows [0,128)  : cost_feat F (stage-3 input, written by stage 2)
    // sX3T rows [128,159): disparity fourier encoding (written in gather phase)
    __shared__ float sX3T[K3 * PAD];
    __shared__ float sHT[K2 * PAD];
    __shared__ int sSeed[BM];

    const int tid = threadIdx.x;
    const int blk = blockIdx.x;
    const int p0 = blk * (BM / NSEED);  // first pixel of this block
    const int row0 = blk * BM;          // first global row (n*NS + s ordering)

    if (tid < BM) sSeed[tid] = label_seed[row0 + tid];
    __syncthreads();

    // ---- gather cost -> sX3T rows [0, 72) ----
    // cost[n, s, g*9+c] = cost_volume[n, g, clip(seed[n,s] + c - 4, 0, 63)]
    for (int e = tid; e < K1 * BM; e += 256) {
        const int k = e >> 6;    // 0..71
        const int row = e & 63;  // local row
        const int sd = sSeed[row];
        const int g = k / 9;
        const int c = k - g * 9;
        int d = sd + c - 4;
        d = d < 0 ? 0 : (d > DD - 1 ? DD - 1 : d);
        const int n = p0 + (row >> 2);
        sX3T[k * PAD + row] = cost_volume[(size_t)n * (GG * DD) + g * DD + d];
    }

    // ---- fourier disparity encoding -> sX3T rows [128, 159) ----
    for (int e = tid; e < 31 * BM; e += 256) {
        const int j = e >> 6;
        const int row = e & 63;
        const float coord = (float)sSeed[row] * (float)(3.14 / 64.0);
        float v;
        if (j < NFREQ)
            v = sinf(coord * (float)(1 << j));
        else if (j < 2 * NFREQ)
            v = cosf(coord * (float)(1 << (j - NFREQ)));
        else
            v = coord;
        sX3T[(K2 + j) * PAD + row] = v;
    }

    // ---- label_f output (second tuple element) ----
    if (tid < BM) out[(size_t)RTOT * EE + row0 + tid] = (float)sSeed[tid];
    __syncthreads();

    const int tx = tid & 15;  // 16 col groups x 8 cols
    const int ty = tid >> 4;  // 16 row groups x 4 rows

    float acc[4][8];

    // ---- stage 1: h = gelu(cost @ W1 + b1) ----
#pragma unroll
    for (int r = 0; r < 4; ++r)
#pragma unroll
        for (int c = 0; c < 8; ++c) acc[r][c] = 0.0f;
    mm_tile<K1>(sX3T, W1, tx, ty, acc);
    {
        const float4 bA = *(const float4*)(b1 + tx * 8);
        const float4 bB = *(const float4*)(b1 + tx * 8 + 4);
        const float bb[8] = {bA.x, bA.y, bA.z, bA.w, bB.x, bB.y, bB.z, bB.w};
#pragma unroll
        for (int c = 0; c < 8; ++c) {
            float4 v;
            v.x = gelu_exact(acc[0][c] + bb[c]);
            v.y = gelu_exact(acc[1][c] + bb[c]);
            v.z = gelu_exact(acc[2][c] + bb[c]);
            v.w = gelu_exact(acc[3][c] + bb[c]);
            *(float4*)(sHT + (tx * 8 + c) * PAD + ty * 4) = v;
        }
    }
    __syncthreads();

    // ---- stage 2: F = h @ W2 + b2  -> sX3T rows [0,128) ----
#pragma unroll
    for (int r = 0; r < 4; ++r)
#pragma unroll
        for (int c = 0; c < 8; ++c) acc[r][c] = 0.0f;
    mm_tile<K2>(sHT, W2, tx, ty, acc);
    {
        const float4 bA = *(const float4*)(b2 + tx * 8);
        const float4 bB = *(const float4*)(b2 + tx * 8 + 4);
        const float bb[8] = {bA.x, bA.y, bA.z, bA.w, bB.x, bB.y, bB.z, bB.w};
#pragma unroll
        for (int c = 0; c < 8; ++c) {
            float4 v;
            v.x = acc[0][c] + bb[c];
            v.y = acc[1][c] + bb[c];
            v.z = acc[2][c] + bb[c];
            v.w = acc[3][c] + bb[c];
            *(float4*)(sX3T + (tx * 8 + c) * PAD + ty * 4) = v;
        }
    }
    __syncthreads();

    // ---- stage 3: out = [F | disp_enc] @ Wp ----
#pragma unroll
    for (int r = 0; r < 4; ++r)
#pragma unroll
        for (int c = 0; c < 8; ++c) acc[r][c] = 0.0f;
    mm_tile<K3>(sX3T, Wp, tx, ty, acc);
#pragma unroll
    for (int r = 0; r < 4; ++r) {
        const size_t grow = (size_t)(row0 + ty * 4 + r);
        float4 v0 = {acc[r][0], acc[r][1], acc[r][2], acc[r][3]};
        float4 v1 = {acc[r][4], acc[r][5], acc[r][6], acc[r][7]};
        *(float4*)(out + grow * EE + tx * 8) = v0;
        *(float4*)(out + grow * EE + tx * 8 + 4) = v1;
    }
}

extern "C" void kernel_launch(void* const* d_in, const int* in_sizes, int n_in,
                              void* d_out, int out_size, void* d_ws, size_t ws_size,
                              hipStream_t stream) {
    const float* cost_volume = (const float*)d_in[0];
    const int* label_seed = (const int*)d_in[1];
    // d_in[2] = context: unused by reference (layers=[], norm=None -> passthrough)
    const float* W1 = (const float*)d_in[3];
    const float* b1 = (const float*)d_in[4];
    const float* W2 = (const float*)d_in[5];
    const float* b2 = (const float*)d_in[6];
    const float* Wp = (const float*)d_in[7];
    float* out = (float*)d_out;

    dim3 grid(RTOT / BM);  // 6400 blocks
    Propagation_85315230368231_kernel<<<grid, 256, 0, stream>>>(
        cost_volume, label_seed, W1, b1, W2, b2, Wp, out);
}

// Round 2
// 461.340 us; speedup vs baseline: 2.1726x; 2.1726x over previous
//
#include <hip/hip_runtime.h>
#include <hip/hip_bf16.h>
#include <math.h>

// Problem constants
#define NPIX 102400          // B*H*W
#define NSEED 4
#define RTOT (NPIX * NSEED)  // 409600 rows
#define GG 8
#define DD 64
#define EE 128
#define BM 64                // rows per block (16 pixels x 4 seeds)

// Padded K dims (multiples of 32 for 16x16x32 MFMA)
#define KP1 96               // 72 -> 96
#define KP2 128
#define KP3 160              // 159 -> 160

// LDS row strides (shorts). All chosen so row stride in dwords mod 32 gives
// <=2-way bank aliasing (free per m136) and rows stay 16B-aligned.
#define PC 104               // sCost stride  (52 dw, 20m mod 32: 2-way)
#define PH 136               // sHT stride    (68 dw,  4m mod 32: 2-way)
#define PF 168               // sFT stride    (84 dw, 20m mod 32: 2-way)

typedef short bf16x8 __attribute__((ext_vector_type(8)));
typedef short bf16x4 __attribute__((ext_vector_type(4)));
typedef float f32x4 __attribute__((ext_vector_type(4)));

static __device__ __forceinline__ short f2bf(float x) {
    __hip_bfloat16 h = __float2bfloat16(x);  // RNE
    return __builtin_bit_cast(short, h);
}

static __device__ __forceinline__ float gelu_exact(float x) {
    return 0.5f * x * (1.0f + erff(x * 0.7071067811865475f));
}

// ---- pre-pass: transpose + bf16-cast weights into d_ws ----
// ws layout (shorts): W1T [128][96] @0 | W2T [128][128] @12288 | WpT [128][160] @28672
__global__ void prep_weights(const float* __restrict__ W1,
                             const float* __restrict__ W2,
                             const float* __restrict__ Wp,
                             short* __restrict__ ws) {
    const int i = blockIdx.x * 256 + threadIdx.x;  // grid covers 49152
    if (i < 12288) {
        const int e = i / KP1, k = i - e * KP1;
        ws[i] = (k < 72) ? f2bf(W1[k * EE + e]) : (short)0;
    } else if (i < 12288 + 16384) {
        const int j = i - 12288;
        const int e = j / KP2, k = j - e * KP2;
        ws[i] = f2bf(W2[k * EE + e]);
    } else if (i < 49152) {
        const int j = i - 28672;
        const int e = j / KP3, k = j - e * KP3;
        ws[i] = (k < 159) ? f2bf(Wp[k * EE + e]) : (short)0;
    }
}

// One K-stage of D^T = W^T(A) x act^T(B). Wave handles m-tiles {mt0,mt0+1} x n-tiles 0..3.
template <int KPAD, int PADB>
__device__ __forceinline__ void gemm_tiles(const short* __restrict__ WT, const short* sB,
                                           int mt0, int ln, int qd, f32x4 acc[2][4]) {
#pragma unroll
    for (int ks = 0; ks < KPAD / 32; ++ks) {
        const int kb = ks * 32 + qd * 8;
        const bf16x8 a0 = *(const bf16x8*)(WT + (mt0 * 16 + ln) * KPAD + kb);
        const bf16x8 a1 = *(const bf16x8*)(WT + (mt0 * 16 + 16 + ln) * KPAD + kb);
        const bf16x8 b0 = *(const bf16x8*)(sB + (0 * 16 + ln) * PADB + kb);
        const bf16x8 b1 = *(const bf16x8*)(sB + (1 * 16 + ln) * PADB + kb);
        const bf16x8 b2 = *(const bf16x8*)(sB + (2 * 16 + ln) * PADB + kb);
        const bf16x8 b3 = *(const bf16x8*)(sB + (3 * 16 + ln) * PADB + kb);
        acc[0][0] = __builtin_amdgcn_mfma_f32_16x16x32_bf16(a0, b0, acc[0][0], 0, 0, 0);
        acc[0][1] = __builtin_amdgcn_mfma_f32_16x16x32_bf16(a0, b1, acc[0][1], 0, 0, 0);
        acc[0][2] = __builtin_amdgcn_mfma_f32_16x16x32_bf16(a0, b2, acc[0][2], 0, 0, 0);
        acc[0][3] = __builtin_amdgcn_mfma_f32_16x16x32_bf16(a0, b3, acc[0][3], 0, 0, 0);
        acc[1][0] = __builtin_amdgcn_mfma_f32_16x16x32_bf16(a1, b0, acc[1][0], 0, 0, 0);
        acc[1][1] = __builtin_amdgcn_mfma_f32_16x16x32_bf16(a1, b1, acc[1][1], 0, 0, 0);
        acc[1][2] = __builtin_amdgcn_mfma_f32_16x16x32_bf16(a1, b2, acc[1][2], 0, 0, 0);
        acc[1][3] = __builtin_amdgcn_mfma_f32_16x16x32_bf16(a1, b3, acc[1][3], 0, 0, 0);
    }
}

__global__ __launch_bounds__(256, 4)
void Propagation_85315230368231_kernel(const float* __restrict__ cost_volume,
                                       const int* __restrict__ label_seed,
                                       const short* __restrict__ ws,
                                       const float* __restrict__ b1,
                                       const float* __restrict__ b2,
                                       float* __restrict__ out) {
    // sU: union buffer. Phase A: gathered cost, row-major [64][PC] bf16 (k 0..95).
    //     Phase B: stage-3 input [F^T | disp_enc], row-major [64][PF] bf16 (k 0..159).
    __shared__ short sU[BM * PF];     // 21504 B
    __shared__ short sHT[BM * PH];    // 17408 B
    __shared__ int sSeed[BM];

    const short* W1T = ws;
    const short* W2T = ws + 12288;
    const short* WpT = ws + 28672;

    const int tid = threadIdx.x;
    const int blk = blockIdx.x;
    const int p0 = blk * (BM / NSEED);
    const int row0 = blk * BM;

    const int wave = tid >> 6;
    const int lane = tid & 63;
    const int ln = lane & 15;
    const int qd = lane >> 4;
    const int mt0 = wave * 2;

    if (tid < BM) {
        const int sd = label_seed[row0 + tid];
        sSeed[tid] = sd;
        out[(size_t)RTOT * EE + row0 + tid] = (float)sd;  // label_f output
    }
    __syncthreads();

    // ---- gather cost -> sU rows, stride PC, bf16 pairs ----
    for (int e = tid; e < BM * 36; e += 256) {
        const int row = e / 36;
        const int pr = e - row * 36;
        const int k0 = pr * 2, k1 = k0 + 1;
        const int sd = sSeed[row];
        const float* cvn = cost_volume + (size_t)(p0 + (row >> 2)) * (GG * DD);
        const int g0 = k0 / 9, c0 = k0 - g0 * 9;
        int d0 = sd + c0 - 4; d0 = d0 < 0 ? 0 : (d0 > 63 ? 63 : d0);
        const float v0 = cvn[g0 * DD + d0];
        const int g1 = k1 / 9, c1 = k1 - g1 * 9;
        int d1 = sd + c1 - 4; d1 = d1 < 0 ? 0 : (d1 > 63 ? 63 : d1);
        const float v1 = cvn[g1 * DD + d1];
        const int pk = (int)(unsigned short)f2bf(v0) | ((int)(unsigned short)f2bf(v1) << 16);
        *(int*)(sU + row * PC + k0) = pk;
    }
    // zero-pad k = 72..95
    for (int e = tid; e < BM * 12; e += 256) {
        const int row = e / 12;
        const int j = e - row * 12;
        *(int*)(sU + row * PC + 72 + 2 * j) = 0;
    }
    __syncthreads();  // (1) gather visible

    f32x4 acc[2][4];

    // ---- stage 1: h^T = gelu(W1T x cost^T + b1) -> sHT [row][e1] ----
#pragma unroll
    for (int i = 0; i < 2; ++i)
#pragma unroll
        for (int j = 0; j < 4; ++j) acc[i][j] = (f32x4)0.0f;
    gemm_tiles<KP1, PC>(W1T, sU, mt0, ln, qd, acc);
#pragma unroll
    for (int mi = 0; mi < 2; ++mi) {
        const int eb = (mt0 + mi) * 16 + qd * 4;
        const float4 bv = *(const float4*)(b1 + eb);
#pragma unroll
        for (int nt = 0; nt < 4; ++nt) {
            bf16x4 p;
            p[0] = f2bf(gelu_exact(acc[mi][nt][0] + bv.x));
            p[1] = f2bf(gelu_exact(acc[mi][nt][1] + bv.y));
            p[2] = f2bf(gelu_exact(acc[mi][nt][2] + bv.z));
            p[3] = f2bf(gelu_exact(acc[mi][nt][3] + bv.w));
            *(bf16x4*)(sHT + (nt * 16 + ln) * PH + eb) = p;
        }
    }
    __syncthreads();  // (2) sHT visible; all stage-1 sU reads done

    // ---- fourier disparity encoding -> sU cols [128,160) (stride PF now) ----
    for (int e = tid; e < BM * 32; e += 256) {
        const int row = e >> 5;
        const int j = e & 31;
        const float coord = (float)sSeed[row] * (float)(3.14 / 64.0);
        float v;
        if (j < 15) v = sinf(coord * (float)(1 << j));
        else if (j < 30) v = cosf(coord * (float)(1 << (j - 15)));
        else if (j == 30) v = coord;
        else v = 0.0f;  // k=159 pad
        sU[row * PF + 128 + j] = f2bf(v);
    }

    // ---- stage 2: F^T = W2T x h^T + b2 -> sU cols [0,128) ----
#pragma unroll
    for (int i = 0; i < 2; ++i)
#pragma unroll
        for (int j = 0; j < 4; ++j) acc[i][j] = (f32x4)0.0f;
    gemm_tiles<KP2, PH>(W2T, sHT, mt0, ln, qd, acc);
#pragma unroll
    for (int mi = 0; mi < 2; ++mi) {
        const int eb = (mt0 + mi) * 16 + qd * 4;
        const float4 bv = *(const float4*)(b2 + eb);
#pragma unroll
        for (int nt = 0; nt < 4; ++nt) {
            bf16x4 p;
            p[0] = f2bf(acc[mi][nt][0] + bv.x);
            p[1] = f2bf(acc[mi][nt][1] + bv.y);
            p[2] = f2bf(acc[mi][nt][2] + bv.z);
            p[3] = f2bf(acc[mi][nt][3] + bv.w);
            *(bf16x4*)(sU + (nt * 16 + ln) * PF + eb) = p;
        }
    }
    __syncthreads();  // (3) disp + F visible

    // ---- stage 3: out^T = WpT x [F|disp]^T ----
#pragma unroll
    for (int i = 0; i < 2; ++i)
#pragma unroll
        for (int j = 0; j < 4; ++j) acc[i][j] = (f32x4)0.0f;
    gemm_tiles<KP3, PF>(WpT, sU, mt0, ln, qd, acc);
#pragma unroll
    for (int mi = 0; mi < 2; ++mi) {
        const int eb = (mt0 + mi) * 16 + qd * 4;
#pragma unroll
        for (int nt = 0; nt < 4; ++nt) {
            const size_t grow = (size_t)(row0 + nt * 16 + ln);
            float4 v = {acc[mi][nt][0], acc[mi][nt][1], acc[mi][nt][2], acc[mi][nt][3]};
            *(float4*)(out + grow * EE + eb) = v;
        }
    }
}

extern "C" void kernel_launch(void* const* d_in, const int* in_sizes, int n_in,
                              void* d_out, int out_size, void* d_ws, size_t ws_size,
                              hipStream_t stream) {
    const float* cost_volume = (const float*)d_in[0];
    const int* label_seed = (const int*)d_in[1];
    // d_in[2] = context: unused (layers=[], norm=None)
    const float* W1 = (const float*)d_in[3];
    const float* b1 = (const float*)d_in[4];
    const float* W2 = (const float*)d_in[5];
    const float* b2 = (const float*)d_in[6];
    const float* Wp = (const float*)d_in[7];
    float* out = (float*)d_out;
    short* ws = (short*)d_ws;  // needs 49152 shorts = 96 KB

    prep_weights<<<192, 256, 0, stream>>>(W1, W2, Wp, ws);
    Propagation_85315230368231_kernel<<<RTOT / BM, 256, 0, stream>>>(
        cost_volume, label_seed, ws, b1, b2, out);
}